// Round 2
// baseline (129.418 us; speedup 1.0000x reference)
//
#include <hip/hip_runtime.h>
#include <hip/hip_bf16.h>

#define N 8192
#define D 128
#define NJB 64  // column blocks of 128

typedef __bf16 bf16x8 __attribute__((ext_vector_type(8)));
typedef float f32x4 __attribute__((ext_vector_type(4)));

#define LN2 0.69314718056f

// Kernel 1: row-normalize features (fp32 -> bf16), pre-scale by rsqrt(T*ln2)
// so that downstream acc = logits * log2(e), and build label histogram.
__global__ void k_norm(const float* __restrict__ feat, const int* __restrict__ lab,
                       const float* __restrict__ tempp,
                       __hip_bfloat16* __restrict__ fbf, float* __restrict__ hist) {
    const int row  = blockIdx.x * 4 + (threadIdx.x >> 6);
    const int lane = threadIdx.x & 63;
    float2 v = *reinterpret_cast<const float2*>(&feat[row * D + lane * 2]);
    float ss = v.x * v.x + v.y * v.y;
#pragma unroll
    for (int m = 32; m; m >>= 1) ss += __shfl_xor(ss, m);
    const float sc = rsqrtf(tempp[0] * LN2);  // acc = sim/(T*ln2) = logits*log2e
    const float r = sc / fmaxf(sqrtf(ss), 1e-8f);
    __hip_bfloat162 o;
    o.x = __float2bfloat16(v.x * r);
    o.y = __float2bfloat16(v.y * r);
    *reinterpret_cast<__hip_bfloat162*>(&fbf[row * D + lane * 2]) = o;
    if (lane == 0) atomicAdd(&hist[lab[row]], 1.0f);  // exact fp32 counts
}

// Kernel 2: fused 128x128 MFMA tile + contrastive epilogue, NO LDS staging.
// Inputs are 2 MB bf16 (L2-resident); MFMA fragments load straight from global
// with full 64B-line utilization (16 rows x 1 line per fragment). Epilogue:
// spos = sum acc over same-label cols, edem = sum exp2(acc) over diff-label.
__launch_bounds__(256, 4)
__global__ void k_gemm(const __hip_bfloat16* __restrict__ fbf,
                       const int* __restrict__ lab,
                       float* __restrict__ Pspos, float* __restrict__ Pedem) {
    const int jb = blockIdx.x, ib = blockIdx.y;
    const int i0 = ib * 128, j0 = jb * 128;
    const int tid = threadIdx.x;
    const int wave = tid >> 6, lane = tid & 63;
    const int wm = wave >> 1, wn = wave & 1;   // 2x2 waves, 64x64 each
    const int lr = lane & 15, lg = lane >> 4;

    // Per-lane fragment base pointers (A row = i0+wm*64+mi*16+lr, k = ks*32+lg*8)
    const __hip_bfloat16* pa = fbf + (size_t)(i0 + wm * 64 + lr) * D + lg * 8;
    const __hip_bfloat16* pb = fbf + (size_t)(j0 + wn * 64 + lr) * D + lg * 8;

    f32x4 acc[4][4] = {};
#pragma unroll
    for (int ks = 0; ks < 4; ++ks) {
        bf16x8 af[4], bfr[4];
#pragma unroll
        for (int mi = 0; mi < 4; ++mi)
            af[mi] = *reinterpret_cast<const bf16x8*>(pa + mi * 16 * D + ks * 32);
#pragma unroll
        for (int ni = 0; ni < 4; ++ni)
            bfr[ni] = *reinterpret_cast<const bf16x8*>(pb + ni * 16 * D + ks * 32);
#pragma unroll
        for (int mi = 0; mi < 4; ++mi)
#pragma unroll
            for (int ni = 0; ni < 4; ++ni)
                acc[mi][ni] = __builtin_amdgcn_mfma_f32_16x16x32_bf16(
                    af[mi], bfr[ni], acc[mi][ni], 0, 0, 0);
    }

    // Labels: row labels batched as int4 (rows mi*16 + lg*4 + r are contiguous in r)
    int4 labi[4];
#pragma unroll
    for (int mi = 0; mi < 4; ++mi)
        labi[mi] = *reinterpret_cast<const int4*>(&lab[i0 + wm * 64 + mi * 16 + lg * 4]);
    int labj[4];
#pragma unroll
    for (int ni = 0; ni < 4; ++ni) labj[ni] = lab[j0 + wn * 64 + ni * 16 + lr];

    __shared__ float sred[512];  // [0:256) spos[wn][row], [256:512) edem[wn][row]
    float* sposL = sred;
    float* edemL = sred + 256;

    // C/D layout (m89): col = lane&15, row = (lane>>4)*4 + reg
#pragma unroll
    for (int mi = 0; mi < 4; ++mi) {
#pragma unroll
        for (int r = 0; r < 4; ++r) {
            const int rowl = wm * 64 + mi * 16 + lg * 4 + r;
            const int li = reinterpret_cast<const int*>(&labi[mi])[r];
            float ps = 0.0f, es = 0.0f;
#pragma unroll
            for (int ni = 0; ni < 4; ++ni) {
                float v = acc[mi][ni][r];          // = logits * log2(e)
                bool same = (li == labj[ni]);
                ps += same ? v : 0.0f;
                es += same ? 0.0f : __builtin_amdgcn_exp2f(v);  // exp(logits)
            }
#pragma unroll
            for (int m = 1; m < 16; m <<= 1) {  // reduce across the 16 col lanes
                ps += __shfl_xor(ps, m);
                es += __shfl_xor(es, m);
            }
            if (lr == 0) {
                sposL[wn * 128 + rowl] = ps;
                edemL[wn * 128 + rowl] = es;
            }
        }
    }
    __syncthreads();
    if (tid < 128) {
        float ps = sposL[tid] + sposL[128 + tid];
        float es = edemL[tid] + edemL[128 + tid];
        Pspos[jb * N + i0 + tid] = ps;
        Pedem[jb * N + i0 + tid] = es;
    }
}

// Kernel 3: per-row combine over 64 column-blocks, then per-block partial sum.
// sp is in log2e domain -> multiply by ln2; log(ed) = log2(ed)*ln2.
__global__ void k_row(const float* __restrict__ Pspos, const float* __restrict__ Pedem,
                      const int* __restrict__ lab, const float* __restrict__ hist,
                      float* __restrict__ bsums) {
    const int i = blockIdx.x * 128 + threadIdx.x;
    float sp = 0.0f, ed = 0.0f;
    for (int jb = 0; jb < NJB; ++jb) {
        sp += Pspos[jb * N + i];
        ed += Pedem[jb * N + i];
    }
    const float cnt = hist[lab[i]];
    float term = LN2 * (sp / cnt - __builtin_amdgcn_logf(ed));  // logf builtin = log2
#pragma unroll
    for (int m = 32; m; m >>= 1) term += __shfl_xor(term, m);
    __shared__ float s2[2];
    if ((threadIdx.x & 63) == 0) s2[threadIdx.x >> 6] = term;
    __syncthreads();
    if (threadIdx.x == 0) bsums[blockIdx.x] = s2[0] + s2[1];
}

// Kernel 4: final scalar.
__global__ void k_final(const float* __restrict__ bsums, float* __restrict__ out) {
    float v = bsums[threadIdx.x];  // 64 threads, 64 block sums
#pragma unroll
    for (int m = 32; m; m >>= 1) v += __shfl_xor(v, m);
    if (threadIdx.x == 0) out[0] = -(v / (float)N);
}

extern "C" void kernel_launch(void* const* d_in, const int* in_sizes, int n_in,
                              void* d_out, int out_size, void* d_ws, size_t ws_size,
                              hipStream_t stream) {
    const float* feat = (const float*)d_in[0];
    const int* lab    = (const int*)d_in[1];
    const float* temp = (const float*)d_in[2];
    float* out = (float*)d_out;
    char* ws = (char*)d_ws;

    __hip_bfloat16* fbf = (__hip_bfloat16*)ws;      // 2 MB normalized+scaled bf16
    float* hist  = (float*)(ws + 2097152);          // 512 B label histogram
    float* Pspos = (float*)(ws + 2097664);          // 2 MB partials [64][8192]
    float* Pedem = (float*)(ws + 4194816);          // 2 MB partials [64][8192]
    float* bsums = (float*)(ws + 6291968);          // 256 B

    hipMemsetAsync(hist, 0, 128 * sizeof(float), stream);
    k_norm<<<N / 4, 256, 0, stream>>>(feat, lab, temp, fbf, hist);
    dim3 grid(NJB, N / 128);
    k_gemm<<<grid, 256, 0, stream>>>(fbf, lab, Pspos, Pedem);
    k_row<<<64, 128, 0, stream>>>(Pspos, Pedem, lab, hist, bsums);
    k_final<<<1, 64, 0, stream>>>(bsums, out);
}